// Round 11
// baseline (237.892 us; speedup 1.0000x reference)
//
#include <hip/hip_runtime.h>

#define NF 64
#define ND 32
#define NPAIR 2016
#define SPW 4   // samples per wave, software-pipelined 2-deep

typedef __attribute__((ext_vector_type(8))) short bf16x8;
typedef __attribute__((ext_vector_type(4))) float f32x4;

// R10 post-mortem: all pipes <15% busy, HBM 2.45/6.3 TB/s, yet 81 us — the
// wall is per-wave fixed latency (16384 one-sample waves, ~1 us serial chain
// each, weak cross-wave overlap). Fix: 4096 waves x 4 samples, double-buffered
// register pipeline so sample k+1's global loads fly under sample k's
// split/MFMA/LDS/store. Load & store byte patterns identical to R10
// (validated: WRITE_SIZE == output exactly).
__global__ __launch_bounds__(256, 4) void ip_gram_mfma(
    const float* __restrict__ in, float* __restrict__ out) {

    __shared__ float obuf[4][NPAIR];   // 32256 B; wave-private row, no barriers

    const int t = threadIdx.x;
    const int w = t >> 6;
    const int l = t & 63;
    const int g = blockIdx.x * 4 + w;     // wave id: 1024 blocks * 4 = 4096
    const int s0 = g * SPW;               // first of 4 consecutive samples

    const int q = l >> 4;                 // k-block: lane covers k = 8q..8q+7
    const int m = l & 15;                 // row within each 16-row block

    const float* src0 = in + (size_t)s0 * (NF * ND) + (q << 3);
    float* __restrict__ ob = obuf[w];

    float4 bufA[8], bufB[8];              // [2r]=row half0, [2r+1]=row half1

    auto LOAD = [&](float4* buf, int k) {
        const float* sp = src0 + k * (NF * ND);
        #pragma unroll
        for (int r = 0; r < 4; ++r) {
            const float* rowp = sp + (r * 16 + m) * ND;
            buf[2 * r]     = ((const float4*)rowp)[0];
            buf[2 * r + 1] = ((const float4*)rowp)[1];
        }
    };

    auto PROCESS = [&](const float4* buf, int k) {
        // fp32 -> bf16 hi/lo split (exact residual), same numerics as R10
        bf16x8 fhi[4], flo[4];
        #pragma unroll
        for (int r = 0; r < 4; ++r) {
            float xv[8] = {buf[2*r].x, buf[2*r].y, buf[2*r].z, buf[2*r].w,
                           buf[2*r+1].x, buf[2*r+1].y, buf[2*r+1].z, buf[2*r+1].w};
            #pragma unroll
            for (int e = 0; e < 8; ++e) {
                unsigned xb = __builtin_bit_cast(unsigned, xv[e]);
                fhi[r][e] = (short)(xb >> 16);
                float hf = __builtin_bit_cast(float, xb & 0xFFFF0000u);
                float lf = xv[e] - hf;
                flo[r][e] = (short)(__builtin_bit_cast(unsigned, lf) >> 16);
            }
        }
        // upper tiles -> wave-private LDS row (C/D: row = q*4+reg, col = m)
        #pragma unroll
        for (int ti = 0; ti < 4; ++ti) {
            #pragma unroll
            for (int tj = ti; tj < 4; ++tj) {
                f32x4 c = {0.f, 0.f, 0.f, 0.f};
                c = __builtin_amdgcn_mfma_f32_16x16x32_bf16(fhi[ti], fhi[tj], c, 0, 0, 0);
                c = __builtin_amdgcn_mfma_f32_16x16x32_bf16(fhi[ti], flo[tj], c, 0, 0, 0);
                c = __builtin_amdgcn_mfma_f32_16x16x32_bf16(flo[ti], fhi[tj], c, 0, 0, 0);
                int j = tj * 16 + m;
                #pragma unroll
                for (int r = 0; r < 4; ++r) {
                    int i = ti * 16 + (q << 2) + r;
                    if (ti < tj || j > i) {
                        int p = ((i * (127 - i)) >> 1) + j - i - 1;
                        ob[p] = c[r];
                    }
                }
            }
        }
        // coalesced epilogue: contiguous 8064-B row, dwordx4 stores
        float4* __restrict__ dst4 = (float4*)(out + (size_t)(s0 + k) * NPAIR);
        const float4* __restrict__ ob4 = (const float4*)ob;
        #pragma unroll
        for (int it = 0; it < 8; ++it) {
            int idx4 = l + (it << 6);
            if (idx4 < NPAIR / 4) {
                dst4[idx4] = ob4[idx4];
            }
        }
    };

    // 2-deep pipeline, fully unrolled, static buffer names (no dyn indexing)
    LOAD(bufA, 0);
    LOAD(bufB, 1);
    PROCESS(bufA, 0);
    LOAD(bufA, 2);
    PROCESS(bufB, 1);
    LOAD(bufB, 3);
    PROCESS(bufA, 2);
    PROCESS(bufB, 3);
}

extern "C" void kernel_launch(void* const* d_in, const int* in_sizes, int n_in,
                              void* d_out, int out_size, void* d_ws, size_t ws_size,
                              hipStream_t stream) {
    const float* in = (const float*)d_in[0];
    float* out = (float*)d_out;
    const int nsamples = in_sizes[0] / (NF * ND);   // 16384
    ip_gram_mfma<<<nsamples / (4 * SPW), 256, 0, stream>>>(in, out);
}